// Round 9
// baseline (398.740 us; speedup 1.0000x reference)
//
#include <hip/hip_runtime.h>
#include <math.h>

#define N_ATOMS   50000
#define N_BONDS   500000
#define N_TRIPLES 2000000
#define DD        64
#define RSZ       68   // padded LDS row
#define CAP       16   // bucket capacity per bond (Poisson(4); P(X>16)~4e-6)

typedef float f4v __attribute__((ext_vector_type(4)));
typedef int   i4v __attribute__((ext_vector_type(4)));

// ---------------- workspace layout (bytes) ----------------
#define O_UPD   0u                            // 50000*64*4 = 12,800,000
#define O_CUR   12800000u                     // 500000*4 -> pad 2,000,128
#define O_BKT   (O_CUR + 2000128u)            // 500000*16*8 = 64,000,000
#define O_OVFC  (O_BKT + 64000000u)           // 128 B (overflow counter)
#define O_OVF   (O_OVFC + 128u)               // 2M*12 = 24,000,000 (full capacity)
#define WS_NEED ((size_t)O_OVF + 24000000u)

// ---------------------------------------------------------------------------
// A: upd[a,c] = sigmoid(atom[a,:] @ W_update[:,c] + b_update[c])
// Also zeroes cursor[] (160 ints/block x 3125 blocks) and the overflow ctr.
// ---------------------------------------------------------------------------
__global__ __launch_bounds__(256) void atom_update3_kernel(
    const float* __restrict__ atom, const float* __restrict__ W,
    const float* __restrict__ bb, float* __restrict__ out,
    int* __restrict__ cursor, int* __restrict__ ovf_cnt)
{
    if (cursor != nullptr && threadIdx.x < 160)
        cursor[blockIdx.x * 160 + threadIdx.x] = 0;
    if (ovf_cnt != nullptr && blockIdx.x == 0 && threadIdx.x == 0)
        *ovf_cnt = 0;

    __shared__ float sW[DD * DD];
    __shared__ float sRow[16 * RSZ];
    for (int i = threadIdx.x; i < DD * DD; i += 256) sW[i] = W[i];

    const int wave = threadIdx.x >> 6;
    const int lane = threadIdx.x & 63;
    const int g    = lane >> 4;
    const int c4   = (lane & 15) * 4;
    const int aBase = blockIdx.x * 16 + wave * 4;

    f4v r = *(const f4v*)(atom + (size_t)(aBase + g) * DD + c4);
    *(f4v*)&sRow[(wave * 4 + g) * RSZ + c4] = r;
    __syncthreads();

    float y0 = bb[lane], y1 = y0, y2 = y0, y3 = y0;
    const float* r0 = &sRow[(wave * 4 + 0) * RSZ];
    const float* r1 = &sRow[(wave * 4 + 1) * RSZ];
    const float* r2 = &sRow[(wave * 4 + 2) * RSZ];
    const float* r3 = &sRow[(wave * 4 + 3) * RSZ];
#pragma unroll
    for (int k = 0; k < DD; ++k) {
        float wk = sW[k * DD + lane];
        y0 = fmaf(r0[k], wk, y0);
        y1 = fmaf(r1[k], wk, y1);
        y2 = fmaf(r2[k], wk, y2);
        y3 = fmaf(r3[k], wk, y3);
    }
    size_t o = (size_t)aBase * DD + lane;
    out[o]          = 1.0f / (1.0f + __expf(-y0));
    out[o + DD]     = 1.0f / (1.0f + __expf(-y1));
    out[o + 2*DD]   = 1.0f / (1.0f + __expf(-y2));
    out[o + 3*DD]   = 1.0f / (1.0f + __expf(-y3));
}

// ---------------------------------------------------------------------------
// B: direct bucket fill — one pass, no count/scan.
// ---------------------------------------------------------------------------
__global__ __launch_bounds__(256) void fill_bucket_kernel(
    const i4v* __restrict__ tbi4, const int* __restrict__ bai,
    int* __restrict__ cursor, int2* __restrict__ pairs,
    int* __restrict__ ovf_cnt, int* __restrict__ ovf)
{
    int i = blockIdx.x * 256 + threadIdx.x;
    if (i >= N_TRIPLES / 2) return;
    i4v v = __builtin_nontemporal_load(tbi4 + i);  // (dst0,src0,dst1,src1)
    int a0 = bai[2 * v.y + 1];
    int a1 = bai[2 * v.w + 1];

    int s0 = atomicAdd(&cursor[v.x], 1);
    if (s0 < CAP) {
        pairs[(size_t)v.x * CAP + s0] = make_int2(2 * i, a0);
    } else {
        int o = atomicAdd(ovf_cnt, 1);
        ovf[3 * o] = v.x; ovf[3 * o + 1] = 2 * i; ovf[3 * o + 2] = a0;
    }
    int s1 = atomicAdd(&cursor[v.z], 1);
    if (s1 < CAP) {
        pairs[(size_t)v.z * CAP + s1] = make_int2(2 * i + 1, a1);
    } else {
        int o = atomicAdd(ovf_cnt, 1);
        ovf[3 * o] = v.z; ovf[3 * o + 1] = 2 * i + 1; ovf[3 * o + 2] = a1;
    }
}

// ---------------------------------------------------------------------------
// C: gather + segment-sum + fused (@W_fuse + b_fuse + bond_features).
// 16-lane group per bond, BRANCH-FREE gather: 8 slots per round, all loads
// unconditional (clamped slot index + range-clamped px/py), validity applied
// as a value mask. Compiler can cluster 8 basis + 8 upd loads -> one
// latency exposure per round; 92% of waves do exactly 1 round.
// ---------------------------------------------------------------------------
__global__ __launch_bounds__(256) void gather_fuse6_kernel(
    const float* __restrict__ basis, const float* __restrict__ upd,
    const int2* __restrict__ pairs, const int* __restrict__ cnts,
    const int* __restrict__ ovf_cnt, const int* __restrict__ ovf,
    const float* __restrict__ bond, const float* __restrict__ W,
    const float* __restrict__ bb, float* __restrict__ out)
{
    __shared__ float sW[DD * DD];
    __shared__ float sRow[16 * RSZ];
    for (int i = threadIdx.x; i < DD * DD; i += 256) sW[i] = W[i];

    const int wave = threadIdx.x >> 6;
    const int lane = threadIdx.x & 63;
    const int g    = lane >> 4;          // group -> bond within wave
    const int c4   = (lane & 15) * 4;    // channel quad
    const int bBase = blockIdx.x * 16 + wave * 4;
    const int myB   = bBase + g;

    int cntRaw = cnts[myB];
    int cnt    = min(cntRaw, CAP);
    int wm = cnt;
    wm = max(wm, __shfl_xor(wm, 16, 64));
    wm = max(wm, __shfl_xor(wm, 32, 64));

    // prefetch bond rows + bias early
    size_t ob = (size_t)bBase * DD + lane;
    float bv0 = __builtin_nontemporal_load(bond + ob);
    float bv1 = __builtin_nontemporal_load(bond + ob + DD);
    float bv2 = __builtin_nontemporal_load(bond + ob + 2 * DD);
    float bv3 = __builtin_nontemporal_load(bond + ob + 3 * DD);
    float bias = bb[lane];

    const int2* bkt = pairs + (size_t)myB * CAP;
    const f4v z = (f4v){0.f,0.f,0.f,0.f};
    f4v acc = z;

#pragma unroll
    for (int r = 0; r < 2; ++r) {
        if (r * 8 < wm) {
            // slot pair words: group-uniform address -> L1 broadcast
            int2 p[8];
#pragma unroll
            for (int i = 0; i < 8; ++i) {
                int s  = r * 8 + i;
                int sc = max(0, min(s, cnt - 1));
                p[i] = bkt[sc];
            }
            // unconditional clamped loads: full MLP, no control flow
            f4v bs[8], uu[8];
#pragma unroll
            for (int i = 0; i < 8; ++i) {
                unsigned px = (unsigned)p[i].x; if (px >= N_TRIPLES) px = 0;
                unsigned py = (unsigned)p[i].y; if (py >= N_ATOMS)   py = 0;
                bs[i] = __builtin_nontemporal_load(
                    (const f4v*)(basis + (size_t)px * DD + c4));
                uu[i] = *(const f4v*)(upd + (size_t)py * DD + c4);
            }
#pragma unroll
            for (int i = 0; i < 8; ++i) {
                int s = r * 8 + i;
                acc += (s < cnt) ? (bs[i] * uu[i]) : z;
            }
        }
    }

    // overflow replay (novf ~ 0-2 for CAP=16)
    int novf = *ovf_cnt;
    if (novf > 0) {
        for (int i = 0; i < novf; ++i) {
            int dst = ovf[3 * i];
            if (dst == myB) {
                int t = ovf[3 * i + 1], a = ovf[3 * i + 2];
                f4v bs = *(const f4v*)(basis + (size_t)t * DD + c4);
                f4v uu = *(const f4v*)(upd + (size_t)a * DD + c4);
                acc += bs * uu;
            }
        }
    }

    *(f4v*)&sRow[(wave * 4 + g) * RSZ + c4] = acc;
    __syncthreads();

    float y0 = bias, y1 = bias, y2 = bias, y3 = bias;
    const float* r0 = &sRow[(wave * 4 + 0) * RSZ];
    const float* r1 = &sRow[(wave * 4 + 1) * RSZ];
    const float* r2 = &sRow[(wave * 4 + 2) * RSZ];
    const float* r3 = &sRow[(wave * 4 + 3) * RSZ];
#pragma unroll
    for (int k4 = 0; k4 < DD / 4; ++k4) {
        f4v a0 = *(const f4v*)&r0[k4 * 4];   // ds_read_b128 broadcast
        f4v a1 = *(const f4v*)&r1[k4 * 4];
        f4v a2 = *(const f4v*)&r2[k4 * 4];
        f4v a3 = *(const f4v*)&r3[k4 * 4];
#pragma unroll
        for (int kk = 0; kk < 4; ++kk) {
            float wk = sW[(k4 * 4 + kk) * DD + lane];
            y0 = fmaf(a0[kk], wk, y0);
            y1 = fmaf(a1[kk], wk, y1);
            y2 = fmaf(a2[kk], wk, y2);
            y3 = fmaf(a3[kk], wk, y3);
        }
    }
    __builtin_nontemporal_store(bv0 + y0, out + ob);
    __builtin_nontemporal_store(bv1 + y1, out + ob + DD);
    __builtin_nontemporal_store(bv2 + y2, out + ob + 2 * DD);
    __builtin_nontemporal_store(bv3 + y3, out + ob + 3 * DD);
}

// ---------------------------------------------------------------------------
// Fallback path (ws too small): atomic scatter + separate fuse
// ---------------------------------------------------------------------------
__global__ __launch_bounds__(256) void scatter_kernel(
    const float* __restrict__ basis, const float* __restrict__ upd,
    const int* __restrict__ tbi, const int* __restrict__ bai,
    float* __restrict__ summed)
{
    int t  = blockIdx.x * 16 + (threadIdx.x >> 4);
    int c0 = (threadIdx.x & 15) * 4;
    int dst = tbi[2 * t];
    int src = tbi[2 * t + 1];
    int a   = bai[2 * src + 1];
    const float4 bs = *reinterpret_cast<const float4*>(basis + (size_t)t * DD + c0);
    const float4 uu = *reinterpret_cast<const float4*>(upd   + (size_t)a * DD + c0);
    float* p = summed + (size_t)dst * DD + c0;
    atomicAdd(p + 0, bs.x * uu.x);
    atomicAdd(p + 1, bs.y * uu.y);
    atomicAdd(p + 2, bs.z * uu.z);
    atomicAdd(p + 3, bs.w * uu.w);
}

__global__ __launch_bounds__(256) void fuse_kernel(
    const float* __restrict__ bond, const float* __restrict__ W,
    const float* __restrict__ b, float* __restrict__ io)
{
    __shared__ float sW[DD * DD];
    __shared__ float sRow[4 * DD];
    for (int i = threadIdx.x; i < DD * DD; i += 256) sW[i] = W[i];
    size_t base = (size_t)blockIdx.x * (4 * DD);
    sRow[threadIdx.x] = io[base + threadIdx.x];
    __syncthreads();
    int local = threadIdx.x >> 6;
    int c     = threadIdx.x & 63;
    float sum = b[c];
#pragma unroll
    for (int k = 0; k < DD; ++k)
        sum = fmaf(sRow[local * DD + k], sW[k * DD + c], sum);
    io[base + threadIdx.x] = bond[base + threadIdx.x] + sum;
}

extern "C" void kernel_launch(void* const* d_in, const int* in_sizes, int n_in,
                              void* d_out, int out_size, void* d_ws, size_t ws_size,
                              hipStream_t stream) {
    const float* atom  = (const float*)d_in[0];
    const float* bond  = (const float*)d_in[1];
    const float* basis = (const float*)d_in[2];
    const int*   bai   = (const int*)d_in[3];
    const int*   tbi   = (const int*)d_in[4];
    const float* Wu    = (const float*)d_in[5];
    const float* bu    = (const float*)d_in[6];
    const float* Wf    = (const float*)d_in[7];
    const float* bf    = (const float*)d_in[8];

    float* out = (float*)d_out;
    char*  ws  = (char*)d_ws;

    float* upd     = (float*)(ws + O_UPD);
    int*   cursor  = (int*)  (ws + O_CUR);
    int2*  pairs   = (int2*) (ws + O_BKT);
    int*   ovf_cnt = (int*)  (ws + O_OVFC);
    int*   ovf     = (int*)  (ws + O_OVF);

    if (ws_size >= WS_NEED) {
        atom_update3_kernel<<<N_ATOMS / 16, 256, 0, stream>>>(
            atom, Wu, bu, upd, cursor, ovf_cnt);
        fill_bucket_kernel<<<(N_TRIPLES / 2 + 255) / 256, 256, 0, stream>>>(
            (const i4v*)tbi, bai, cursor, pairs, ovf_cnt, ovf);
        gather_fuse6_kernel<<<N_BONDS / 16, 256, 0, stream>>>(
            basis, upd, pairs, cursor, ovf_cnt, ovf, bond, Wf, bf, out);
    } else {
        atom_update3_kernel<<<N_ATOMS / 16, 256, 0, stream>>>(
            atom, Wu, bu, upd, nullptr, nullptr);
        hipMemsetAsync(out, 0, (size_t)N_BONDS * DD * sizeof(float), stream);
        scatter_kernel<<<N_TRIPLES / 16, 256, 0, stream>>>(basis, upd, tbi, bai, out);
        fuse_kernel<<<N_BONDS / 4, 256, 0, stream>>>(bond, Wf, bf, out);
    }
}

// Round 10
// 358.131 us; speedup vs baseline: 1.1134x; 1.1134x over previous
//
#include <hip/hip_runtime.h>
#include <math.h>

#define N_ATOMS   50000
#define N_BONDS   500000
#define N_TRIPLES 2000000
#define DD        64
#define RSZ       68   // padded LDS row
#define CAP       16   // bucket capacity per bond (Poisson(4); P(X>16)~4e-6)

#define ATOM_BLKS (N_ATOMS / 16)                       // 3125
#define FILL_BLKS ((N_TRIPLES / 2 + 255) / 256)        // 3907

typedef float f4v __attribute__((ext_vector_type(4)));
typedef int   i4v __attribute__((ext_vector_type(4)));

// ---------------- workspace layout (bytes) ----------------
#define O_UPD   0u                            // 50000*64*4 = 12,800,000
#define O_CUR   12800000u                     // cursor 2,000,000 + ovf_cnt + pad
#define O_BKT   (O_CUR + 2000128u)            // 500000*16*8 = 64,000,000
#define O_OVF   (O_BKT + 64000000u)           // 2M*12 = 24,000,000 (full capacity)
#define WS_NEED ((size_t)O_OVF + 24000000u)

// ---------------------------------------------------------------------------
// Fused A+B: blocks [0, ATOM_BLKS) compute
//   upd[a,c] = sigmoid(atom[a,:] @ W_update[:,c] + b_update[c]);
// blocks [ATOM_BLKS, ATOM_BLKS+FILL_BLKS) do the direct bucket fill
//   (2 triples/thread). cursor/ovf_cnt are pre-zeroed by a memset node.
// The two halves use disjoint pipes (LDS/VALU vs atomics/L2) and overlap.
// ---------------------------------------------------------------------------
__global__ __launch_bounds__(256) void fused_atom_fill_kernel(
    const float* __restrict__ atom, const float* __restrict__ W,
    const float* __restrict__ bb, float* __restrict__ upd,
    const i4v* __restrict__ tbi4, const int* __restrict__ bai,
    int* __restrict__ cursor, int2* __restrict__ pairs,
    int* __restrict__ ovf_cnt, int* __restrict__ ovf)
{
    __shared__ float sW[DD * DD];
    __shared__ float sRow[16 * RSZ];

    if (blockIdx.x < ATOM_BLKS) {
        // ---------------- atom update ----------------
        for (int i = threadIdx.x; i < DD * DD; i += 256) sW[i] = W[i];

        const int wave = threadIdx.x >> 6;
        const int lane = threadIdx.x & 63;
        const int g    = lane >> 4;
        const int c4   = (lane & 15) * 4;
        const int aBase = blockIdx.x * 16 + wave * 4;

        f4v r = *(const f4v*)(atom + (size_t)(aBase + g) * DD + c4);
        *(f4v*)&sRow[(wave * 4 + g) * RSZ + c4] = r;
        __syncthreads();

        float y0 = bb[lane], y1 = y0, y2 = y0, y3 = y0;
        const float* r0 = &sRow[(wave * 4 + 0) * RSZ];
        const float* r1 = &sRow[(wave * 4 + 1) * RSZ];
        const float* r2 = &sRow[(wave * 4 + 2) * RSZ];
        const float* r3 = &sRow[(wave * 4 + 3) * RSZ];
#pragma unroll
        for (int k = 0; k < DD; ++k) {
            float wk = sW[k * DD + lane];
            y0 = fmaf(r0[k], wk, y0);
            y1 = fmaf(r1[k], wk, y1);
            y2 = fmaf(r2[k], wk, y2);
            y3 = fmaf(r3[k], wk, y3);
        }
        size_t o = (size_t)aBase * DD + lane;
        upd[o]          = 1.0f / (1.0f + __expf(-y0));
        upd[o + DD]     = 1.0f / (1.0f + __expf(-y1));
        upd[o + 2*DD]   = 1.0f / (1.0f + __expf(-y2));
        upd[o + 3*DD]   = 1.0f / (1.0f + __expf(-y3));
    } else {
        // ---------------- bucket fill ----------------
        int i = (blockIdx.x - ATOM_BLKS) * 256 + threadIdx.x;
        if (i >= N_TRIPLES / 2) return;
        i4v v = __builtin_nontemporal_load(tbi4 + i);  // (dst0,src0,dst1,src1)
        int a0 = bai[2 * v.y + 1];
        int a1 = bai[2 * v.w + 1];

        int s0 = atomicAdd(&cursor[v.x], 1);
        if (s0 < CAP) {
            pairs[(size_t)v.x * CAP + s0] = make_int2(2 * i, a0);
        } else {
            int o = atomicAdd(ovf_cnt, 1);
            ovf[3 * o] = v.x; ovf[3 * o + 1] = 2 * i; ovf[3 * o + 2] = a0;
        }
        int s1 = atomicAdd(&cursor[v.z], 1);
        if (s1 < CAP) {
            pairs[(size_t)v.z * CAP + s1] = make_int2(2 * i + 1, a1);
        } else {
            int o = atomicAdd(ovf_cnt, 1);
            ovf[3 * o] = v.z; ovf[3 * o + 1] = 2 * i + 1; ovf[3 * o + 2] = a1;
        }
    }
}

// ---------------------------------------------------------------------------
// C: gather + segment-sum + fused (@W_fuse + b_fuse + bond_features).
// Wave = 4 bonds, 16-lane group per bond. Lane l preloads bucket slot
// (l&15) of its group's bond in one coalesced 512B wave load. 4 slots per
// round, group-uniform exec-mask guards (cheap), single accumulator per
// group -> no segmented accs, no butterfly folds. (Round-8 v5 — fastest.)
// ---------------------------------------------------------------------------
__global__ __launch_bounds__(256) void gather_fuse5_kernel(
    const float* __restrict__ basis, const float* __restrict__ upd,
    const int2* __restrict__ pairs, const int* __restrict__ cnts,
    const int* __restrict__ ovf_cnt, const int* __restrict__ ovf,
    const float* __restrict__ bond, const float* __restrict__ W,
    const float* __restrict__ bb, float* __restrict__ out)
{
    __shared__ float sW[DD * DD];
    __shared__ float sRow[16 * RSZ];
    for (int i = threadIdx.x; i < DD * DD; i += 256) sW[i] = W[i];

    const int wave = threadIdx.x >> 6;
    const int lane = threadIdx.x & 63;
    const int g    = lane >> 4;          // group -> bond within wave
    const int c4   = (lane & 15) * 4;    // channel quad
    const int bBase = blockIdx.x * 16 + wave * 4;
    const int myB   = bBase + g;

    int cntRaw = cnts[myB];
    int cnt    = min(cntRaw, CAP);
    int wm = cnt;
    wm = max(wm, __shfl_xor(wm, 16, 64));
    wm = max(wm, __shfl_xor(wm, 32, 64));

    // prefetch bond rows + bias early
    size_t ob = (size_t)bBase * DD + lane;
    float bv0 = __builtin_nontemporal_load(bond + ob);
    float bv1 = __builtin_nontemporal_load(bond + ob + DD);
    float bv2 = __builtin_nontemporal_load(bond + ob + 2 * DD);
    float bv3 = __builtin_nontemporal_load(bond + ob + 3 * DD);
    float bias = bb[lane];

    // coalesced preload: lane l holds slot (l&15) of its group's bucket
    int2 myp = pairs[(size_t)myB * CAP + (lane & 15)];

    const f4v z = (f4v){0.f,0.f,0.f,0.f};
    f4v acc = z;
    for (int r = 0; r * 4 < wm; ++r) {
#pragma unroll
        for (int i = 0; i < 4; ++i) {
            int s  = r * 4 + i;
            int px = __shfl(myp.x, g * 16 + s, 64);
            int py = __shfl(myp.y, g * 16 + s, 64);
            if (s < cnt) {
                f4v bs = __builtin_nontemporal_load(
                    (const f4v*)(basis + (size_t)px * DD + c4));
                f4v uu = *(const f4v*)(upd + (size_t)py * DD + c4);
                acc += bs * uu;
            }
        }
    }

    // overflow replay (novf == 0 essentially always)
    int novf = *ovf_cnt;
    if (novf > 0) {
        for (int i = 0; i < novf; ++i) {
            int dst = ovf[3 * i];
            if (dst == myB) {
                int t = ovf[3 * i + 1], a = ovf[3 * i + 2];
                f4v bs = *(const f4v*)(basis + (size_t)t * DD + c4);
                f4v uu = *(const f4v*)(upd + (size_t)a * DD + c4);
                acc += bs * uu;
            }
        }
    }

    *(f4v*)&sRow[(wave * 4 + g) * RSZ + c4] = acc;
    __syncthreads();

    float y0 = bias, y1 = bias, y2 = bias, y3 = bias;
    const float* r0 = &sRow[(wave * 4 + 0) * RSZ];
    const float* r1 = &sRow[(wave * 4 + 1) * RSZ];
    const float* r2 = &sRow[(wave * 4 + 2) * RSZ];
    const float* r3 = &sRow[(wave * 4 + 3) * RSZ];
#pragma unroll
    for (int k4 = 0; k4 < DD / 4; ++k4) {
        f4v a0 = *(const f4v*)&r0[k4 * 4];   // ds_read_b128 broadcast
        f4v a1 = *(const f4v*)&r1[k4 * 4];
        f4v a2 = *(const f4v*)&r2[k4 * 4];
        f4v a3 = *(const f4v*)&r3[k4 * 4];
#pragma unroll
        for (int kk = 0; kk < 4; ++kk) {
            float wk = sW[(k4 * 4 + kk) * DD + lane];
            y0 = fmaf(a0[kk], wk, y0);
            y1 = fmaf(a1[kk], wk, y1);
            y2 = fmaf(a2[kk], wk, y2);
            y3 = fmaf(a3[kk], wk, y3);
        }
    }
    __builtin_nontemporal_store(bv0 + y0, out + ob);
    __builtin_nontemporal_store(bv1 + y1, out + ob + DD);
    __builtin_nontemporal_store(bv2 + y2, out + ob + 2 * DD);
    __builtin_nontemporal_store(bv3 + y3, out + ob + 3 * DD);
}

// ---------------------------------------------------------------------------
// Fallback path (ws too small): atom update + atomic scatter + fuse
// ---------------------------------------------------------------------------
__global__ __launch_bounds__(256) void atom_update_fb_kernel(
    const float* __restrict__ atom, const float* __restrict__ W,
    const float* __restrict__ bb, float* __restrict__ out)
{
    __shared__ float sW[DD * DD];
    __shared__ float sRow[16 * RSZ];
    for (int i = threadIdx.x; i < DD * DD; i += 256) sW[i] = W[i];

    const int wave = threadIdx.x >> 6;
    const int lane = threadIdx.x & 63;
    const int g    = lane >> 4;
    const int c4   = (lane & 15) * 4;
    const int aBase = blockIdx.x * 16 + wave * 4;

    f4v r = *(const f4v*)(atom + (size_t)(aBase + g) * DD + c4);
    *(f4v*)&sRow[(wave * 4 + g) * RSZ + c4] = r;
    __syncthreads();

    float y0 = bb[lane], y1 = y0, y2 = y0, y3 = y0;
    const float* r0 = &sRow[(wave * 4 + 0) * RSZ];
    const float* r1 = &sRow[(wave * 4 + 1) * RSZ];
    const float* r2 = &sRow[(wave * 4 + 2) * RSZ];
    const float* r3 = &sRow[(wave * 4 + 3) * RSZ];
#pragma unroll
    for (int k = 0; k < DD; ++k) {
        float wk = sW[k * DD + lane];
        y0 = fmaf(r0[k], wk, y0);
        y1 = fmaf(r1[k], wk, y1);
        y2 = fmaf(r2[k], wk, y2);
        y3 = fmaf(r3[k], wk, y3);
    }
    size_t o = (size_t)aBase * DD + lane;
    out[o]          = 1.0f / (1.0f + __expf(-y0));
    out[o + DD]     = 1.0f / (1.0f + __expf(-y1));
    out[o + 2*DD]   = 1.0f / (1.0f + __expf(-y2));
    out[o + 3*DD]   = 1.0f / (1.0f + __expf(-y3));
}

__global__ __launch_bounds__(256) void scatter_kernel(
    const float* __restrict__ basis, const float* __restrict__ upd,
    const int* __restrict__ tbi, const int* __restrict__ bai,
    float* __restrict__ summed)
{
    int t  = blockIdx.x * 16 + (threadIdx.x >> 4);
    int c0 = (threadIdx.x & 15) * 4;
    int dst = tbi[2 * t];
    int src = tbi[2 * t + 1];
    int a   = bai[2 * src + 1];
    const float4 bs = *reinterpret_cast<const float4*>(basis + (size_t)t * DD + c0);
    const float4 uu = *reinterpret_cast<const float4*>(upd   + (size_t)a * DD + c0);
    float* p = summed + (size_t)dst * DD + c0;
    atomicAdd(p + 0, bs.x * uu.x);
    atomicAdd(p + 1, bs.y * uu.y);
    atomicAdd(p + 2, bs.z * uu.z);
    atomicAdd(p + 3, bs.w * uu.w);
}

__global__ __launch_bounds__(256) void fuse_kernel(
    const float* __restrict__ bond, const float* __restrict__ W,
    const float* __restrict__ b, float* __restrict__ io)
{
    __shared__ float sW[DD * DD];
    __shared__ float sRow[4 * DD];
    for (int i = threadIdx.x; i < DD * DD; i += 256) sW[i] = W[i];
    size_t base = (size_t)blockIdx.x * (4 * DD);
    sRow[threadIdx.x] = io[base + threadIdx.x];
    __syncthreads();
    int local = threadIdx.x >> 6;
    int c     = threadIdx.x & 63;
    float sum = b[c];
#pragma unroll
    for (int k = 0; k < DD; ++k)
        sum = fmaf(sRow[local * DD + k], sW[k * DD + c], sum);
    io[base + threadIdx.x] = bond[base + threadIdx.x] + sum;
}

extern "C" void kernel_launch(void* const* d_in, const int* in_sizes, int n_in,
                              void* d_out, int out_size, void* d_ws, size_t ws_size,
                              hipStream_t stream) {
    const float* atom  = (const float*)d_in[0];
    const float* bond  = (const float*)d_in[1];
    const float* basis = (const float*)d_in[2];
    const int*   bai   = (const int*)d_in[3];
    const int*   tbi   = (const int*)d_in[4];
    const float* Wu    = (const float*)d_in[5];
    const float* bu    = (const float*)d_in[6];
    const float* Wf    = (const float*)d_in[7];
    const float* bf    = (const float*)d_in[8];

    float* out = (float*)d_out;
    char*  ws  = (char*)d_ws;

    float* upd     = (float*)(ws + O_UPD);
    int*   cursor  = (int*)  (ws + O_CUR);
    int*   ovf_cnt = cursor + N_BONDS;            // inside the memset span
    int2*  pairs   = (int2*) (ws + O_BKT);
    int*   ovf     = (int*)  (ws + O_OVF);

    if (ws_size >= WS_NEED) {
        // 1) zero cursor + ovf_cnt in one small memset node (2 MB)
        hipMemsetAsync(cursor, 0, (size_t)(N_BONDS + 32) * sizeof(int), stream);
        // 2) fused atom-update + bucket-fill (independent halves, overlap)
        fused_atom_fill_kernel<<<ATOM_BLKS + FILL_BLKS, 256, 0, stream>>>(
            atom, Wu, bu, upd, (const i4v*)tbi, bai, cursor, pairs, ovf_cnt, ovf);
        // 3) gather + segment-sum + fused epilogue (round-8 v5 structure)
        gather_fuse5_kernel<<<N_BONDS / 16, 256, 0, stream>>>(
            basis, upd, pairs, cursor, ovf_cnt, ovf, bond, Wf, bf, out);
    } else {
        atom_update_fb_kernel<<<N_ATOMS / 16, 256, 0, stream>>>(atom, Wu, bu, upd);
        hipMemsetAsync(out, 0, (size_t)N_BONDS * DD * sizeof(float), stream);
        scatter_kernel<<<N_TRIPLES / 16, 256, 0, stream>>>(basis, upd, tbi, bai, out);
        fuse_kernel<<<N_BONDS / 4, 256, 0, stream>>>(bond, Wf, bf, out);
    }
}

// Round 12
// 340.117 us; speedup vs baseline: 1.1724x; 1.0530x over previous
//
#include <hip/hip_runtime.h>
#include <math.h>

#define N_ATOMS   50000
#define N_BONDS   500000
#define N_TRIPLES 2000000
#define DD        64
#define RSZ       64   // LDS row (no pad: writes 2-way alias=free, reads broadcast)
#define CAP       16   // bucket capacity per bond (Poisson(4); P(X>16)~4e-6)

#define ATOM_BLKS (N_ATOMS / 16)                       // 3125
#define FILL_BLKS ((N_TRIPLES / 2 + 255) / 256)        // 3907

typedef float f4v __attribute__((ext_vector_type(4)));
typedef int   i4v __attribute__((ext_vector_type(4)));

// ---------------- workspace layout (bytes) ----------------
#define O_UPD   0u                            // 50000*64*4 = 12,800,000
#define O_CUR   12800000u                     // cursor 2,000,000 + ovf_cnt + pad
#define O_BKT   (O_CUR + 2000128u)            // 500000*16*8 = 64,000,000
#define O_OVF   (O_BKT + 64000000u)           // 2M*12 = 24,000,000
#define WS_NEED ((size_t)O_OVF + 24000000u)

// ---------------------------------------------------------------------------
// Fused A+B: blocks [0, ATOM_BLKS) compute
//   upd[a,c] = sigmoid(atom[a,:] @ W_update[:,c] + b_update[c]);
// blocks [ATOM_BLKS, ...) do the direct bucket fill (2 triples/thread).
// cursor/ovf_cnt pre-zeroed by a small memset node.
// ---------------------------------------------------------------------------
__global__ __launch_bounds__(256) void fused_atom_fill_kernel(
    const float* __restrict__ atom, const float* __restrict__ W,
    const float* __restrict__ bb, float* __restrict__ upd,
    const i4v* __restrict__ tbi4, const int* __restrict__ bai,
    int* __restrict__ cursor, int2* __restrict__ pairs,
    int* __restrict__ ovf_cnt, int* __restrict__ ovf)
{
    __shared__ float sW[DD * DD];
    __shared__ float sRow[16 * RSZ];

    if (blockIdx.x < ATOM_BLKS) {
        // ---------------- atom update ----------------
        for (int i = threadIdx.x; i < DD * DD; i += 256) sW[i] = W[i];

        const int wave = threadIdx.x >> 6;
        const int lane = threadIdx.x & 63;
        const int g    = lane >> 4;
        const int c4   = (lane & 15) * 4;
        const int aBase = blockIdx.x * 16 + wave * 4;

        f4v r = *(const f4v*)(atom + (size_t)(aBase + g) * DD + c4);
        *(f4v*)&sRow[(wave * 4 + g) * RSZ + c4] = r;
        __syncthreads();

        float y0 = bb[lane], y1 = y0, y2 = y0, y3 = y0;
        const float* r0 = &sRow[(wave * 4 + 0) * RSZ];
        const float* r1 = &sRow[(wave * 4 + 1) * RSZ];
        const float* r2 = &sRow[(wave * 4 + 2) * RSZ];
        const float* r3 = &sRow[(wave * 4 + 3) * RSZ];
#pragma unroll
        for (int k = 0; k < DD; ++k) {
            float wk = sW[k * DD + lane];
            y0 = fmaf(r0[k], wk, y0);
            y1 = fmaf(r1[k], wk, y1);
            y2 = fmaf(r2[k], wk, y2);
            y3 = fmaf(r3[k], wk, y3);
        }
        size_t o = (size_t)aBase * DD + lane;
        upd[o]          = 1.0f / (1.0f + __expf(-y0));
        upd[o + DD]     = 1.0f / (1.0f + __expf(-y1));
        upd[o + 2*DD]   = 1.0f / (1.0f + __expf(-y2));
        upd[o + 3*DD]   = 1.0f / (1.0f + __expf(-y3));
    } else {
        // ---------------- bucket fill ----------------
        int i = (blockIdx.x - ATOM_BLKS) * 256 + threadIdx.x;
        if (i >= N_TRIPLES / 2) return;
        i4v v = __builtin_nontemporal_load(tbi4 + i);  // (dst0,src0,dst1,src1)
        int a0 = bai[2 * v.y + 1];
        int a1 = bai[2 * v.w + 1];

        int s0 = atomicAdd(&cursor[v.x], 1);
        if (s0 < CAP) {
            pairs[(size_t)v.x * CAP + s0] = make_int2(2 * i, a0);
        } else {
            int o = atomicAdd(ovf_cnt, 1);
            ovf[3 * o] = v.x; ovf[3 * o + 1] = 2 * i; ovf[3 * o + 2] = a0;
        }
        int s1 = atomicAdd(&cursor[v.z], 1);
        if (s1 < CAP) {
            pairs[(size_t)v.z * CAP + s1] = make_int2(2 * i + 1, a1);
        } else {
            int o = atomicAdd(ovf_cnt, 1);
            ovf[3 * o] = v.z; ovf[3 * o + 1] = 2 * i + 1; ovf[3 * o + 2] = a1;
        }
    }
}

// ---------------------------------------------------------------------------
// C: gather + segment-sum + fused (@W_fuse + b_fuse + bond_features).
// Round-8 v5 structure (proven fastest) + LDS trimmed to 20480B and
// launch_bounds(256,8): 8 blocks/CU -> more waves -> more outstanding
// random 256B reads.
// ---------------------------------------------------------------------------
__global__ __launch_bounds__(256, 8) void gather_fuse5_kernel(
    const float* __restrict__ basis, const float* __restrict__ upd,
    const int2* __restrict__ pairs, const int* __restrict__ cnts,
    const int* __restrict__ ovf_cnt, const int* __restrict__ ovf,
    const float* __restrict__ bond, const float* __restrict__ W,
    const float* __restrict__ bb, float* __restrict__ out)
{
    __shared__ float sW[DD * DD];
    __shared__ float sRow[16 * RSZ];
    for (int i = threadIdx.x; i < DD * DD; i += 256) sW[i] = W[i];

    const int wave = threadIdx.x >> 6;
    const int lane = threadIdx.x & 63;
    const int g    = lane >> 4;          // group -> bond within wave
    const int c4   = (lane & 15) * 4;    // channel quad
    const int bBase = blockIdx.x * 16 + wave * 4;
    const int myB   = bBase + g;

    int cntRaw = cnts[myB];
    int cnt    = min(cntRaw, CAP);
    int wm = cnt;
    wm = max(wm, __shfl_xor(wm, 16, 64));
    wm = max(wm, __shfl_xor(wm, 32, 64));

    // prefetch bond rows + bias early
    size_t ob = (size_t)bBase * DD + lane;
    float bv0 = __builtin_nontemporal_load(bond + ob);
    float bv1 = __builtin_nontemporal_load(bond + ob + DD);
    float bv2 = __builtin_nontemporal_load(bond + ob + 2 * DD);
    float bv3 = __builtin_nontemporal_load(bond + ob + 3 * DD);
    float bias = bb[lane];

    // coalesced preload: lane l holds slot (l&15) of its group's bucket
    int2 myp = pairs[(size_t)myB * CAP + (lane & 15)];

    const f4v z = (f4v){0.f,0.f,0.f,0.f};
    f4v acc = z;
    for (int r = 0; r * 4 < wm; ++r) {
#pragma unroll
        for (int i = 0; i < 4; ++i) {
            int s  = r * 4 + i;
            int px = __shfl(myp.x, g * 16 + s, 64);
            int py = __shfl(myp.y, g * 16 + s, 64);
            if (s < cnt) {
                f4v bs = __builtin_nontemporal_load(
                    (const f4v*)(basis + (size_t)px * DD + c4));
                f4v uu = *(const f4v*)(upd + (size_t)py * DD + c4);
                acc += bs * uu;
            }
        }
    }

    // overflow replay (novf == 0 essentially always)
    int novf = *ovf_cnt;
    if (novf > 0) {
        for (int i = 0; i < novf; ++i) {
            int dst = ovf[3 * i];
            if (dst == myB) {
                int t = ovf[3 * i + 1], a = ovf[3 * i + 2];
                f4v bs = *(const f4v*)(basis + (size_t)t * DD + c4);
                f4v uu = *(const f4v*)(upd + (size_t)a * DD + c4);
                acc += bs * uu;
            }
        }
    }

    *(f4v*)&sRow[(wave * 4 + g) * RSZ + c4] = acc;
    __syncthreads();

    float y0 = bias, y1 = bias, y2 = bias, y3 = bias;
    const float* r0 = &sRow[(wave * 4 + 0) * RSZ];
    const float* r1 = &sRow[(wave * 4 + 1) * RSZ];
    const float* r2 = &sRow[(wave * 4 + 2) * RSZ];
    const float* r3 = &sRow[(wave * 4 + 3) * RSZ];
#pragma unroll
    for (int k4 = 0; k4 < DD / 4; ++k4) {
        f4v a0 = *(const f4v*)&r0[k4 * 4];   // ds_read_b128 broadcast
        f4v a1 = *(const f4v*)&r1[k4 * 4];
        f4v a2 = *(const f4v*)&r2[k4 * 4];
        f4v a3 = *(const f4v*)&r3[k4 * 4];
#pragma unroll
        for (int kk = 0; kk < 4; ++kk) {
            float wk = sW[(k4 * 4 + kk) * DD + lane];
            y0 = fmaf(a0[kk], wk, y0);
            y1 = fmaf(a1[kk], wk, y1);
            y2 = fmaf(a2[kk], wk, y2);
            y3 = fmaf(a3[kk], wk, y3);
        }
    }
    __builtin_nontemporal_store(bv0 + y0, out + ob);
    __builtin_nontemporal_store(bv1 + y1, out + ob + DD);
    __builtin_nontemporal_store(bv2 + y2, out + ob + 2 * DD);
    __builtin_nontemporal_store(bv3 + y3, out + ob + 3 * DD);
}

// ---------------------------------------------------------------------------
// Fallback path (ws too small): atom update + atomic scatter + fuse
// ---------------------------------------------------------------------------
__global__ __launch_bounds__(256) void atom_update_fb_kernel(
    const float* __restrict__ atom, const float* __restrict__ W,
    const float* __restrict__ bb, float* __restrict__ out)
{
    __shared__ float sW[DD * DD];
    __shared__ float sRow[16 * RSZ];
    for (int i = threadIdx.x; i < DD * DD; i += 256) sW[i] = W[i];

    const int wave = threadIdx.x >> 6;
    const int lane = threadIdx.x & 63;
    const int g    = lane >> 4;
    const int c4   = (lane & 15) * 4;
    const int aBase = blockIdx.x * 16 + wave * 4;

    f4v r = *(const f4v*)(atom + (size_t)(aBase + g) * DD + c4);
    *(f4v*)&sRow[(wave * 4 + g) * RSZ + c4] = r;
    __syncthreads();

    float y0 = bb[lane], y1 = y0, y2 = y0, y3 = y0;
    const float* r0 = &sRow[(wave * 4 + 0) * RSZ];
    const float* r1 = &sRow[(wave * 4 + 1) * RSZ];
    const float* r2 = &sRow[(wave * 4 + 2) * RSZ];
    const float* r3 = &sRow[(wave * 4 + 3) * RSZ];
#pragma unroll
    for (int k = 0; k < DD; ++k) {
        float wk = sW[k * DD + lane];
        y0 = fmaf(r0[k], wk, y0);
        y1 = fmaf(r1[k], wk, y1);
        y2 = fmaf(r2[k], wk, y2);
        y3 = fmaf(r3[k], wk, y3);
    }
    size_t o = (size_t)aBase * DD + lane;
    out[o]          = 1.0f / (1.0f + __expf(-y0));
    out[o + DD]     = 1.0f / (1.0f + __expf(-y1));
    out[o + 2*DD]   = 1.0f / (1.0f + __expf(-y2));
    out[o + 3*DD]   = 1.0f / (1.0f + __expf(-y3));
}

__global__ __launch_bounds__(256) void scatter_kernel(
    const float* __restrict__ basis, const float* __restrict__ upd,
    const int* __restrict__ tbi, const int* __restrict__ bai,
    float* __restrict__ summed)
{
    int t  = blockIdx.x * 16 + (threadIdx.x >> 4);
    int c0 = (threadIdx.x & 15) * 4;
    int dst = tbi[2 * t];
    int src = tbi[2 * t + 1];
    int a   = bai[2 * src + 1];
    const float4 bs = *reinterpret_cast<const float4*>(basis + (size_t)t * DD + c0);
    const float4 uu = *reinterpret_cast<const float4*>(upd   + (size_t)a * DD + c0);
    float* p = summed + (size_t)dst * DD + c0;
    atomicAdd(p + 0, bs.x * uu.x);
    atomicAdd(p + 1, bs.y * uu.y);
    atomicAdd(p + 2, bs.z * uu.z);
    atomicAdd(p + 3, bs.w * uu.w);
}

__global__ __launch_bounds__(256) void fuse_kernel(
    const float* __restrict__ bond, const float* __restrict__ W,
    const float* __restrict__ b, float* __restrict__ io)
{
    __shared__ float sW[DD * DD];
    __shared__ float sRow[4 * DD];
    for (int i = threadIdx.x; i < DD * DD; i += 256) sW[i] = W[i];
    size_t base = (size_t)blockIdx.x * (4 * DD);
    sRow[threadIdx.x] = io[base + threadIdx.x];
    __syncthreads();
    int local = threadIdx.x >> 6;
    int c     = threadIdx.x & 63;
    float sum = b[c];
#pragma unroll
    for (int k = 0; k < DD; ++k)
        sum = fmaf(sRow[local * DD + k], sW[k * DD + c], sum);
    io[base + threadIdx.x] = bond[base + threadIdx.x] + sum;
}

extern "C" void kernel_launch(void* const* d_in, const int* in_sizes, int n_in,
                              void* d_out, int out_size, void* d_ws, size_t ws_size,
                              hipStream_t stream) {
    const float* atom  = (const float*)d_in[0];
    const float* bond  = (const float*)d_in[1];
    const float* basis = (const float*)d_in[2];
    const int*   bai   = (const int*)d_in[3];
    const int*   tbi   = (const int*)d_in[4];
    const float* Wu    = (const float*)d_in[5];
    const float* bu    = (const float*)d_in[6];
    const float* Wf    = (const float*)d_in[7];
    const float* bf    = (const float*)d_in[8];

    float* out = (float*)d_out;
    char*  ws  = (char*)d_ws;

    float* upd     = (float*)(ws + O_UPD);
    int*   cursor  = (int*)  (ws + O_CUR);
    int*   ovf_cnt = cursor + N_BONDS;            // inside the memset span
    int2*  pairs   = (int2*) (ws + O_BKT);
    int*   ovf     = (int*)  (ws + O_OVF);

    if (ws_size >= WS_NEED) {
        // 1) zero cursor + ovf_cnt in one small memset node (2 MB)
        hipMemsetAsync(cursor, 0, (size_t)(N_BONDS + 32) * sizeof(int), stream);
        // 2) fused atom-update + bucket-fill (independent halves, overlap)
        fused_atom_fill_kernel<<<ATOM_BLKS + FILL_BLKS, 256, 0, stream>>>(
            atom, Wu, bu, upd, (const i4v*)tbi, bai, cursor, pairs, ovf_cnt, ovf);
        // 3) gather + segment-sum + fused epilogue
        gather_fuse5_kernel<<<N_BONDS / 16, 256, 0, stream>>>(
            basis, upd, pairs, cursor, ovf_cnt, ovf, bond, Wf, bf, out);
    } else {
        atom_update_fb_kernel<<<N_ATOMS / 16, 256, 0, stream>>>(atom, Wu, bu, upd);
        hipMemsetAsync(out, 0, (size_t)N_BONDS * DD * sizeof(float), stream);
        scatter_kernel<<<N_TRIPLES / 16, 256, 0, stream>>>(basis, upd, tbi, bai, out);
        fuse_kernel<<<N_BONDS / 4, 256, 0, stream>>>(bond, Wf, bf, out);
    }
}